// Round 2
// baseline (142.825 us; speedup 1.0000x reference)
//
#include <hip/hip_runtime.h>
#include <cmath>

// Problem constants (B=4,S=1024,D=1024,O=1024,E=8,R=16,TOP_K=2)
#define M_TOK 4096
#define KD    1024
#define KEXT  1152     // 1024 + E*R
#define NOUT  1024
#define ERDIM 128      // E*R
#define SCALING 2.0f   // 32/16

typedef short bf16x8 __attribute__((ext_vector_type(8)));
typedef float f32x4  __attribute__((ext_vector_type(4)));

__device__ __forceinline__ ushort f2bf(float f) {
    union { float f; unsigned u; } v; v.f = f;
    unsigned r = v.u + 0x7fffu + ((v.u >> 16) & 1u);
    return (ushort)(r >> 16);
}

// async 16B global->LDS. NOTE: address-space conversion requires C-style
// casts (static_cast is rejected by clang for AS changes).
typedef const unsigned int __attribute__((address_space(1)))* gas_ptr;
typedef unsigned int __attribute__((address_space(3)))* las_ptr;
__device__ __forceinline__ void gld_lds16(const ushort* g, ushort* l) {
    __builtin_amdgcn_global_load_lds((gas_ptr)g, (las_ptr)l, 16, 0, 0);
}

// ---------------------------------------------------------------------------
// Pack B-side operands to bf16:
//   Bext[o][0:1024]        = base_w[o][d]
//   Bext[o][1024+e*16+r]   = lora_B[e][r][o]   (lora_B^T columns)
//   LAT[e*16+r][d]         = lora_A[e][d][r]   (B^T layout for ax GEMM)
// ---------------------------------------------------------------------------
__global__ __launch_bounds__(256) void prep_pack(
    const float* __restrict__ base_w, const float* __restrict__ lora_A,
    const float* __restrict__ lora_B, ushort* __restrict__ Bext,
    ushort* __restrict__ LAT)
{
    int i = blockIdx.x * 256 + threadIdx.x;
    const int NB = NOUT * KEXT;               // 1,179,648
    if (i < NB) {
        int o = i / KEXT;
        int c = i - o * KEXT;
        float v = (c < KD) ? base_w[(size_t)o * KD + c]
                           : lora_B[(size_t)(c - KD) * NOUT + o];
        Bext[i] = f2bf(v);
    } else {
        int j = i - NB;                       // 0 .. 131071
        int er = j >> 10, d = j & 1023;
        int e = er >> 4, r = er & 15;
        LAT[j] = f2bf(lora_A[((size_t)e * KD + d) * 16 + r]);
    }
}

// ---------------------------------------------------------------------------
// Per-token: x -> bf16 into Aext[:,0:1024]; fp32/fp64 router logits;
// top-2 mask + softmax -> wgt[t][e] = SCALING * softmax_weight
// ---------------------------------------------------------------------------
__global__ __launch_bounds__(256) void convert_router(
    const float* __restrict__ x, const float* __restrict__ rw,
    const float* __restrict__ rb, ushort* __restrict__ Aext,
    float* __restrict__ wgt)
{
    const int t   = blockIdx.x;
    const int tid = threadIdx.x;
    const float4 xv = ((const float4*)(x + (size_t)t * KD))[tid];

    ushort4 xb;
    xb.x = f2bf(xv.x); xb.y = f2bf(xv.y); xb.z = f2bf(xv.z); xb.w = f2bf(xv.w);
    ((ushort4*)(Aext + (size_t)t * KEXT))[tid] = xb;

    double p[8];
    #pragma unroll
    for (int e = 0; e < 8; e++) {
        const float4 wv = ((const float4*)(rw + (size_t)e * KD))[tid];
        p[e] = (double)(xv.x * wv.x) + (double)(xv.y * wv.y) +
               (double)(xv.z * wv.z) + (double)(xv.w * wv.w);
    }
    #pragma unroll
    for (int e = 0; e < 8; e++)
        #pragma unroll
        for (int off = 32; off > 0; off >>= 1)
            p[e] += __shfl_xor(p[e], off);

    __shared__ double red[4][8];
    __shared__ float  lg[8];
    const int wave = tid >> 6, lane = tid & 63;
    if (lane == 0) {
        #pragma unroll
        for (int e = 0; e < 8; e++) red[wave][e] = p[e];
    }
    __syncthreads();
    if (tid < 8) {
        double s = red[0][tid] + red[1][tid] + red[2][tid] + red[3][tid]
                 + (double)rb[tid];
        lg[tid] = (float)s;
    }
    __syncthreads();
    if (tid < 8) {
        float my = lg[tid];
        float m1 = -INFINITY, m2 = -INFINITY;
        #pragma unroll
        for (int i = 0; i < 8; i++) {
            float v = lg[i];
            if (v > m1) { m2 = m1; m1 = v; }
            else if (v > m2) { m2 = v; }
        }
        float denom = 0.f;
        #pragma unroll
        for (int i = 0; i < 8; i++)
            if (lg[i] >= m2) denom += expf(lg[i] - m1);
        float w = (my >= m2) ? expf(my - m1) / denom : 0.f;
        wgt[t * 8 + tid] = SCALING * w;
    }
}

// ---------------------------------------------------------------------------
// m97-style bf16 MFMA GEMM, C = A @ B^T. 128x128 tile, BK=32, 4 waves,
// each wave 64x64 via 4x4 grid of 16x16x32 MFMA frags.
// EPI==0: store fp32 partial (split-K slab, no bias)
// EPI==1: store fp32 + bias to output
// ---------------------------------------------------------------------------
template <int EPI>
__global__ __launch_bounds__(256) void gemm_bt(
    const ushort* __restrict__ A, int lda,
    const ushort* __restrict__ B, int ldb,
    float* __restrict__ C, int ldc,
    const float* __restrict__ bias,
    int k_per_z, int zstride, int ksteps)
{
    __shared__ __attribute__((aligned(16))) ushort As[128 * 32];
    __shared__ __attribute__((aligned(16))) ushort Bs[128 * 32];

    const int tid  = threadIdx.x;
    const int wave = tid >> 6;
    const int lane = tid & 63;
    const int m0 = blockIdx.x * 128;
    const int n0 = blockIdx.y * 128;
    const int k0 = blockIdx.z * k_per_z;
    C += (size_t)blockIdx.z * zstride;

    // staging: each thread stages 2x16B of A and 2x16B of B per K-step
    const int srow = tid >> 2;            // 0..63
    const int skq  = (tid & 3) * 8;       // element offset within BK
    const ushort* aP0 = A + (size_t)(m0 + srow) * lda + k0 + skq;
    const ushort* aP1 = aP0 + (size_t)64 * lda;
    const ushort* bP0 = B + (size_t)(n0 + srow) * ldb + k0 + skq;
    const ushort* bP1 = bP0 + (size_t)64 * ldb;
    ushort* as0 = &As[tid * 8];
    ushort* as1 = &As[(256 + tid) * 8];
    ushort* bs0 = &Bs[tid * 8];
    ushort* bs1 = &Bs[(256 + tid) * 8];

    const int wr = (wave >> 1) * 64;
    const int wc = (wave & 1) * 64;
    const int fm = lane & 15;
    const int kg = (lane >> 4) * 8;

    f32x4 acc[4][4] = {};

    for (int ks = 0; ks < ksteps; ++ks) {
        const int kk = ks * 32;
        gld_lds16(aP0 + kk, as0);
        gld_lds16(aP1 + kk, as1);
        gld_lds16(bP0 + kk, bs0);
        gld_lds16(bP1 + kk, bs1);
        __syncthreads();   // drains vmcnt (global_load_lds) before use

        bf16x8 af[4], bf[4];
        #pragma unroll
        for (int i = 0; i < 4; i++)
            af[i] = *(const bf16x8*)&As[(wr + i * 16 + fm) * 32 + kg];
        #pragma unroll
        for (int i = 0; i < 4; i++)
            bf[i] = *(const bf16x8*)&Bs[(wc + i * 16 + fm) * 32 + kg];
        #pragma unroll
        for (int mi = 0; mi < 4; mi++)
            #pragma unroll
            for (int ni = 0; ni < 4; ni++)
                acc[mi][ni] = __builtin_amdgcn_mfma_f32_16x16x32_bf16(
                    af[mi], bf[ni], acc[mi][ni], 0, 0, 0);
        __syncthreads();   // protect LDS before next stage
    }

    // C/D layout: col = lane&15, row = (lane>>4)*4 + reg   [m89/m91 verified]
    const int rr = (lane >> 4) * 4;
    const int cc = lane & 15;
    #pragma unroll
    for (int ni = 0; ni < 4; ni++) {
        const int col = n0 + wc + ni * 16 + cc;
        const float bv = (EPI == 1) ? bias[col] : 0.0f;
        #pragma unroll
        for (int mi = 0; mi < 4; mi++) {
            const int row = m0 + wr + mi * 16 + rr;
            #pragma unroll
            for (int r = 0; r < 4; r++)
                C[(size_t)(row + r) * ldc + col] = acc[mi][ni][r] + bv;
        }
    }
}

// ---------------------------------------------------------------------------
// Reduce split-K partials of ax, apply SCALING*softmax weight, write bf16
// into Aext[:, 1024:1152]
// ---------------------------------------------------------------------------
__global__ __launch_bounds__(256) void ax_combine(
    const float* __restrict__ part, const float* __restrict__ wgt,
    ushort* __restrict__ Aext)
{
    int i = blockIdx.x * 256 + threadIdx.x;   // 0 .. 524287
    const int t = i >> 7, er = i & 127;
    const int SL = M_TOK * ERDIM;             // 524288
    float s = part[i] + part[i + SL] + part[i + 2 * SL] + part[i + 3 * SL];
    float w = wgt[t * 8 + (er >> 4)];
    Aext[(size_t)t * KEXT + KD + er] = f2bf(s * w);
}

// ---------------------------------------------------------------------------
extern "C" void kernel_launch(void* const* d_in, const int* in_sizes, int n_in,
                              void* d_out, int out_size, void* d_ws, size_t ws_size,
                              hipStream_t stream) {
    const float* x        = (const float*)d_in[0];
    const float* base_w   = (const float*)d_in[1];
    const float* base_b   = (const float*)d_in[2];
    const float* lora_A   = (const float*)d_in[3];
    const float* lora_B   = (const float*)d_in[4];
    const float* router_w = (const float*)d_in[5];
    const float* router_b = (const float*)d_in[6];
    float* out = (float*)d_out;

    // workspace layout (bytes): total ~20.6 MB
    char* ws = (char*)d_ws;
    ushort* Aext = (ushort*)(ws);               // 4096*1152*2 = 9,437,184
    ushort* Bext = (ushort*)(ws + 9437184);     // 1024*1152*2 = 2,359,296
    ushort* LAT  = (ushort*)(ws + 11796480);    //  128*1024*2 =   262,144
    float*  wgt  = (float*) (ws + 12058624);    //   4096*8*4  =   131,072
    float*  part = (float*) (ws + 12189696);    // 4*4096*128*4= 8,388,608

    // 1. pack B-side bf16 operands
    prep_pack<<<5120, 256, 0, stream>>>(base_w, lora_A, lora_B, Bext, LAT);
    // 2. x -> bf16 + fp32 router + top-2 softmax weights
    convert_router<<<4096, 256, 0, stream>>>(x, router_w, router_b, Aext, wgt);
    // 3. ax = x @ lora_A  (M=4096,N=128,K=1024) split-K=4 -> fp32 partials
    gemm_bt<0><<<dim3(32, 1, 4), 256, 0, stream>>>(
        Aext, KEXT, LAT, KD, part, ERDIM, nullptr,
        /*k_per_z=*/256, /*zstride=*/M_TOK * ERDIM, /*ksteps=*/8);
    // 4. sax = bf16(SCALING * w * ax) into Aext[:,1024:1152]
    ax_combine<<<2048, 256, 0, stream>>>(part, wgt, Aext);
    // 5. out = [x|sax] @ [base_w|lora_B^T]^T + bias  (M=4096,N=1024,K=1152)
    gemm_bt<1><<<dim3(32, 8, 1), 256, 0, stream>>>(
        Aext, KEXT, Bext, KEXT, out, NOUT, base_b,
        /*k_per_z=*/0, /*zstride=*/0, /*ksteps=*/36);
}

// Round 3
// 129.622 us; speedup vs baseline: 1.1019x; 1.1019x over previous
//
#include <hip/hip_runtime.h>
#include <cmath>

// Problem constants (B=4,S=1024,D=1024,O=1024,E=8,R=16,TOP_K=2)
#define M_TOK 4096
#define KD    1024
#define KEXT  1152     // 1024 + E*R
#define NOUT  1024
#define ERDIM 128      // E*R
#define SCALING 2.0f   // 32/16

typedef short bf16x8 __attribute__((ext_vector_type(8)));
typedef float f32x4  __attribute__((ext_vector_type(4)));

__device__ __forceinline__ ushort f2bf(float f) {
    union { float f; unsigned u; } v; v.f = f;
    unsigned r = v.u + 0x7fffu + ((v.u >> 16) & 1u);
    return (ushort)(r >> 16);
}

// async 16B global->LDS. C-style casts required for addrspace conversion.
typedef const unsigned int __attribute__((address_space(1)))* gas_ptr;
typedef unsigned int __attribute__((address_space(3)))* las_ptr;
__device__ __forceinline__ void gld_lds16(const ushort* g, ushort* l) {
    __builtin_amdgcn_global_load_lds((gas_ptr)g, (las_ptr)l, 16, 0, 0);
}

// ---------------------------------------------------------------------------
// Fused: blocks [0,4096): per-token x->bf16 + fp32/fp64 router + top-2
//        softmax weights.  blocks [4096,9216): pack base_w / lora_B^T /
//        lora_A^T to bf16.
// ---------------------------------------------------------------------------
__global__ __launch_bounds__(256) void prep_router(
    const float* __restrict__ x, const float* __restrict__ rw,
    const float* __restrict__ rb, const float* __restrict__ base_w,
    const float* __restrict__ lora_A, const float* __restrict__ lora_B,
    ushort* __restrict__ Aext, ushort* __restrict__ Bext,
    ushort* __restrict__ LAT, float* __restrict__ wgt)
{
    const int tid = threadIdx.x;
    if (blockIdx.x >= 4096) {               // ---- pack path ----
        int i = (blockIdx.x - 4096) * 256 + tid;
        const int NB = NOUT * KEXT;         // 1,179,648
        if (i < NB) {
            int o = i / KEXT;
            int c = i - o * KEXT;
            float v = (c < KD) ? base_w[(size_t)o * KD + c]
                               : lora_B[(size_t)(c - KD) * NOUT + o];
            Bext[i] = f2bf(v);
        } else {
            int j = i - NB;                 // 0 .. 131071
            int er = j >> 10, d = j & 1023;
            int e = er >> 4, r = er & 15;
            LAT[j] = f2bf(lora_A[((size_t)e * KD + d) * 16 + r]);
        }
        return;
    }
    // ---- router/convert path ----
    const int t = blockIdx.x;
    const float4 xv = ((const float4*)(x + (size_t)t * KD))[tid];

    ushort4 xb;
    xb.x = f2bf(xv.x); xb.y = f2bf(xv.y); xb.z = f2bf(xv.z); xb.w = f2bf(xv.w);
    ((ushort4*)(Aext + (size_t)t * KEXT))[tid] = xb;

    double p[8];
    #pragma unroll
    for (int e = 0; e < 8; e++) {
        const float4 wv = ((const float4*)(rw + (size_t)e * KD))[tid];
        p[e] = (double)(xv.x * wv.x) + (double)(xv.y * wv.y) +
               (double)(xv.z * wv.z) + (double)(xv.w * wv.w);
    }
    #pragma unroll
    for (int e = 0; e < 8; e++)
        #pragma unroll
        for (int off = 32; off > 0; off >>= 1)
            p[e] += __shfl_xor(p[e], off);

    __shared__ double red[4][8];
    __shared__ float  lg[8];
    const int wave = tid >> 6, lane = tid & 63;
    if (lane == 0) {
        #pragma unroll
        for (int e = 0; e < 8; e++) red[wave][e] = p[e];
    }
    __syncthreads();
    if (tid < 8) {
        double s = red[0][tid] + red[1][tid] + red[2][tid] + red[3][tid]
                 + (double)rb[tid];
        lg[tid] = (float)s;
    }
    __syncthreads();
    if (tid < 8) {
        float my = lg[tid];
        float m1 = -INFINITY, m2 = -INFINITY;
        #pragma unroll
        for (int i = 0; i < 8; i++) {
            float v = lg[i];
            if (v > m1) { m2 = m1; m1 = v; }
            else if (v > m2) { m2 = v; }
        }
        float denom = 0.f;
        #pragma unroll
        for (int i = 0; i < 8; i++)
            if (lg[i] >= m2) denom += expf(lg[i] - m1);
        float w = (my >= m2) ? expf(my - m1) / denom : 0.f;
        wgt[t * 8 + tid] = SCALING * w;
    }
}

// ---------------------------------------------------------------------------
// bf16 MFMA GEMM, C = A @ B^T. 128x128 tile, BK=64, double-buffered LDS,
// XOR-swizzled staging (conflict-free ds_read_b128 at 128B row stride).
// 4 waves, each 64x64 via 4x4 grid of 16x16x32 MFMA.
// EPI==0: store fp32 partial (split-K slab); EPI==1: store fp32 + bias.
// ---------------------------------------------------------------------------
template <int EPI>
__global__ __launch_bounds__(256) void gemm_bt(
    const ushort* __restrict__ A, int lda,
    const ushort* __restrict__ B, int ldb,
    float* __restrict__ C, int ldc,
    const float* __restrict__ bias,
    int k_per_z, int zstride, int ksteps)
{
    __shared__ __attribute__((aligned(16))) ushort As[2][128 * 64];
    __shared__ __attribute__((aligned(16))) ushort Bs[2][128 * 64];

    const int tid  = threadIdx.x;
    const int wave = tid >> 6;
    const int lane = tid & 63;
    const int m0 = blockIdx.x * 128;
    const int n0 = blockIdx.y * 128;
    const int k0 = blockIdx.z * k_per_z;
    C += (size_t)blockIdx.z * zstride;

    // Staging: 128 rows x 64 cols bf16 per operand per step = 16KB.
    // Thread -> (row = tid>>3, seg = tid&7); 4 passes of 32 rows.
    // Source col-group is XOR-swizzled by row so that LDS[row][seg] holds
    // global[row][seg ^ (row&7)]; readers deswizzle. LDS dest stays
    // linear (wave-uniform base + lane*16 — required by global_load_lds).
    const int srow = tid >> 3;               // 0..31
    const int scol = ((tid & 7) ^ (srow & 7)) * 8;
    const ushort* aP = A + (size_t)(m0 + srow) * lda + k0 + scol;
    const ushort* bP = B + (size_t)(n0 + srow) * ldb + k0 + scol;

    const int wr = (wave >> 1) * 64;
    const int wc = (wave & 1) * 64;
    const int fm = lane & 15;
    const int q  = lane >> 4;                // 0..3
    const int rx = fm & 7;                   // read-side swizzle key

    f32x4 acc[4][4] = {};

    // prefetch step 0 into buf 0
    #pragma unroll
    for (int p = 0; p < 4; p++) {
        gld_lds16(aP + (size_t)p * 32 * lda, &As[0][tid * 8 + p * 2048]);
        gld_lds16(bP + (size_t)p * 32 * ldb, &Bs[0][tid * 8 + p * 2048]);
    }

    for (int ks = 0; ks < ksteps; ++ks) {
        __syncthreads();   // drains vmcnt: buf[ks&1] staged; prev compute done
        if (ks + 1 < ksteps) {
            const int kk = (ks + 1) * 64;
            ushort* a_d = &As[(ks + 1) & 1][0];
            ushort* b_d = &Bs[(ks + 1) & 1][0];
            #pragma unroll
            for (int p = 0; p < 4; p++) {
                gld_lds16(aP + kk + (size_t)p * 32 * lda, a_d + tid * 8 + p * 2048);
                gld_lds16(bP + kk + (size_t)p * 32 * ldb, b_d + tid * 8 + p * 2048);
            }
        }
        const ushort* as = &As[ks & 1][0];
        const ushort* bs = &Bs[ks & 1][0];

        bf16x8 af[2][4], bf[2][4];
        #pragma unroll
        for (int kh = 0; kh < 2; kh++)
            #pragma unroll
            for (int i = 0; i < 4; i++) {
                const int sg = ((kh * 4 + q) ^ rx) * 8;
                af[kh][i] = *(const bf16x8*)&as[(wr + i * 16 + fm) * 64 + sg];
                bf[kh][i] = *(const bf16x8*)&bs[(wc + i * 16 + fm) * 64 + sg];
            }
        #pragma unroll
        for (int kh = 0; kh < 2; kh++)
            #pragma unroll
            for (int mi = 0; mi < 4; mi++)
                #pragma unroll
                for (int ni = 0; ni < 4; ni++)
                    acc[mi][ni] = __builtin_amdgcn_mfma_f32_16x16x32_bf16(
                        af[kh][mi], bf[kh][ni], acc[mi][ni], 0, 0, 0);
    }

    // C/D layout: col = lane&15, row = (lane>>4)*4 + reg   [m89/m91 verified]
    const int rr = q * 4;
    const int cc = fm;
    #pragma unroll
    for (int ni = 0; ni < 4; ni++) {
        const int col = n0 + wc + ni * 16 + cc;
        const float bv = (EPI == 1) ? bias[col] : 0.0f;
        #pragma unroll
        for (int mi = 0; mi < 4; mi++) {
            const int row = m0 + wr + mi * 16 + rr;
            #pragma unroll
            for (int r = 0; r < 4; r++)
                C[(size_t)(row + r) * ldc + col] = acc[mi][ni][r] + bv;
        }
    }
}

// ---------------------------------------------------------------------------
// Reduce split-K partials of ax, apply SCALING*softmax weight, write bf16
// into Aext[:, 1024:1152]
// ---------------------------------------------------------------------------
__global__ __launch_bounds__(256) void ax_combine(
    const float* __restrict__ part, const float* __restrict__ wgt,
    ushort* __restrict__ Aext)
{
    int i = blockIdx.x * 256 + threadIdx.x;   // 0 .. 524287
    const int t = i >> 7, er = i & 127;
    const int SL = M_TOK * ERDIM;             // 524288
    float s = part[i] + part[i + SL] + part[i + 2 * SL] + part[i + 3 * SL];
    float w = wgt[t * 8 + (er >> 4)];
    Aext[(size_t)t * KEXT + KD + er] = f2bf(s * w);
}

// ---------------------------------------------------------------------------
extern "C" void kernel_launch(void* const* d_in, const int* in_sizes, int n_in,
                              void* d_out, int out_size, void* d_ws, size_t ws_size,
                              hipStream_t stream) {
    const float* x        = (const float*)d_in[0];
    const float* base_w   = (const float*)d_in[1];
    const float* base_b   = (const float*)d_in[2];
    const float* lora_A   = (const float*)d_in[3];
    const float* lora_B   = (const float*)d_in[4];
    const float* router_w = (const float*)d_in[5];
    const float* router_b = (const float*)d_in[6];
    float* out = (float*)d_out;

    // workspace layout (bytes): total ~20.6 MB
    char* ws = (char*)d_ws;
    ushort* Aext = (ushort*)(ws);               // 4096*1152*2 = 9,437,184
    ushort* Bext = (ushort*)(ws + 9437184);     // 1024*1152*2 = 2,359,296
    ushort* LAT  = (ushort*)(ws + 11796480);    //  128*1024*2 =   262,144
    float*  wgt  = (float*) (ws + 12058624);    //   4096*8*4  =   131,072
    float*  part = (float*) (ws + 12189696);    // 4*4096*128*4= 8,388,608

    // 1. fused: x->bf16 + router weights (blocks 0..4095) and bf16 packing
    //    of base_w / lora_B^T / lora_A^T (blocks 4096..9215)
    prep_router<<<9216, 256, 0, stream>>>(
        x, router_w, router_b, base_w, lora_A, lora_B, Aext, Bext, LAT, wgt);
    // 2. ax = x @ lora_A  (M=4096,N=128,K=1024) split-K=4 -> fp32 partials
    gemm_bt<0><<<dim3(32, 1, 4), 256, 0, stream>>>(
        Aext, KEXT, LAT, KD, part, ERDIM, nullptr,
        /*k_per_z=*/256, /*zstride=*/M_TOK * ERDIM, /*ksteps=*/4);
    // 3. sax = bf16(SCALING * w * ax) into Aext[:,1024:1152]
    ax_combine<<<2048, 256, 0, stream>>>(part, wgt, Aext);
    // 4. out = [x|sax] @ [base_w|lora_B^T]^T + bias  (M=4096,N=1024,K=1152)
    gemm_bt<1><<<dim3(32, 8, 1), 256, 0, stream>>>(
        Aext, KEXT, Bext, KEXT, out, NOUT, base_b,
        /*k_per_z=*/0, /*zstride=*/0, /*ksteps=*/18);
}

// Round 4
// 125.500 us; speedup vs baseline: 1.1381x; 1.0328x over previous
//
#include <hip/hip_runtime.h>
#include <cmath>

// Problem constants (B=4,S=1024,D=1024,O=1024,E=8,R=16,TOP_K=2)
#define M_TOK 4096
#define KD    1024
#define KEXT  1152     // 1024 + E*R
#define NOUT  1024
#define ERDIM 128      // E*R
#define SCALING 2.0f   // 32/16

typedef short bf16x8 __attribute__((ext_vector_type(8)));
typedef float f32x4  __attribute__((ext_vector_type(4)));

__device__ __forceinline__ ushort f2bf(float f) {
    union { float f; unsigned u; } v; v.f = f;
    unsigned r = v.u + 0x7fffu + ((v.u >> 16) & 1u);
    return (ushort)(r >> 16);
}

// async 16B global->LDS. C-style casts required for addrspace conversion.
typedef const unsigned int __attribute__((address_space(1)))* gas_ptr;
typedef unsigned int __attribute__((address_space(3)))* las_ptr;
__device__ __forceinline__ void gld_lds16(const ushort* g, ushort* l) {
    __builtin_amdgcn_global_load_lds((gas_ptr)g, (las_ptr)l, 16, 0, 0);
}

// ---------------------------------------------------------------------------
// Fused: blocks [0,4096): per-token x->bf16 + fp32/fp64 router + top-2
//        softmax weights.  blocks [4096,9216): pack base_w / lora_B^T /
//        lora_A^T to bf16.
// ---------------------------------------------------------------------------
__global__ __launch_bounds__(256) void prep_router(
    const float* __restrict__ x, const float* __restrict__ rw,
    const float* __restrict__ rb, const float* __restrict__ base_w,
    const float* __restrict__ lora_A, const float* __restrict__ lora_B,
    ushort* __restrict__ Aext, ushort* __restrict__ Bext,
    ushort* __restrict__ LAT, float* __restrict__ wgt)
{
    const int tid = threadIdx.x;
    if (blockIdx.x >= 4096) {               // ---- pack path ----
        int i = (blockIdx.x - 4096) * 256 + tid;
        const int NB = NOUT * KEXT;         // 1,179,648
        if (i < NB) {
            int o = i / KEXT;
            int c = i - o * KEXT;
            float v = (c < KD) ? base_w[(size_t)o * KD + c]
                               : lora_B[(size_t)(c - KD) * NOUT + o];
            Bext[i] = f2bf(v);
        } else {
            int j = i - NB;                 // 0 .. 131071
            int er = j >> 10, d = j & 1023;
            int e = er >> 4, r = er & 15;
            LAT[j] = f2bf(lora_A[((size_t)e * KD + d) * 16 + r]);
        }
        return;
    }
    // ---- router/convert path ----
    const int t = blockIdx.x;
    const float4 xv = ((const float4*)(x + (size_t)t * KD))[tid];

    ushort4 xb;
    xb.x = f2bf(xv.x); xb.y = f2bf(xv.y); xb.z = f2bf(xv.z); xb.w = f2bf(xv.w);
    ((ushort4*)(Aext + (size_t)t * KEXT))[tid] = xb;

    double p[8];
    #pragma unroll
    for (int e = 0; e < 8; e++) {
        const float4 wv = ((const float4*)(rw + (size_t)e * KD))[tid];
        p[e] = (double)(xv.x * wv.x) + (double)(xv.y * wv.y) +
               (double)(xv.z * wv.z) + (double)(xv.w * wv.w);
    }
    #pragma unroll
    for (int e = 0; e < 8; e++)
        #pragma unroll
        for (int off = 32; off > 0; off >>= 1)
            p[e] += __shfl_xor(p[e], off);

    __shared__ double red[4][8];
    __shared__ float  lg[8];
    const int wave = tid >> 6, lane = tid & 63;
    if (lane == 0) {
        #pragma unroll
        for (int e = 0; e < 8; e++) red[wave][e] = p[e];
    }
    __syncthreads();
    if (tid < 8) {
        double s = red[0][tid] + red[1][tid] + red[2][tid] + red[3][tid]
                 + (double)rb[tid];
        lg[tid] = (float)s;
    }
    __syncthreads();
    if (tid < 8) {
        float my = lg[tid];
        float m1 = -INFINITY, m2 = -INFINITY;
        #pragma unroll
        for (int i = 0; i < 8; i++) {
            float v = lg[i];
            if (v > m1) { m2 = m1; m1 = v; }
            else if (v > m2) { m2 = v; }
        }
        float denom = 0.f;
        #pragma unroll
        for (int i = 0; i < 8; i++)
            if (lg[i] >= m2) denom += expf(lg[i] - m1);
        float w = (my >= m2) ? expf(my - m1) / denom : 0.f;
        wgt[t * 8 + tid] = SCALING * w;
    }
}

// ---------------------------------------------------------------------------
// bf16 MFMA GEMM, C = A @ B^T.  Tile (WM*32) x 128, BK=64, double-buffered
// LDS, XOR-swizzled staging (bank-uniform ds_read_b128 at 128B row stride).
// Block = WM*2 waves; each wave computes 32x64 via 2x4 frags of 16x16x32.
//   WM=4: 512 threads, 128x128 tile (main GEMM, 2 waves/SIMD at grid 256)
//   WM=2: 256 threads,  64x128 tile (ax GEMM, grid 256 over all CUs)
// EPI==0: store fp32 partial (split-K slab); EPI==1: store fp32 + bias.
// ---------------------------------------------------------------------------
template <int WM, int EPI>
__global__ __launch_bounds__(WM * 128) void gemm_bt(
    const ushort* __restrict__ A, int lda,
    const ushort* __restrict__ B, int ldb,
    float* __restrict__ C, int ldc,
    const float* __restrict__ bias,
    int k_per_z, int zstride, int ksteps)
{
    constexpr int THREADS = WM * 128;
    constexpr int TM = WM * 32;      // tile rows
    constexpr int PB = 8 / WM;       // B staging passes (A is always 2)

    __shared__ __attribute__((aligned(16))) ushort As[2][TM * 64];
    __shared__ __attribute__((aligned(16))) ushort Bs[2][128 * 64];

    const int tid  = threadIdx.x;
    const int wave = tid >> 6;
    const int lane = tid & 63;
    const int m0 = blockIdx.x * TM;
    const int n0 = blockIdx.y * 128;
    const int k0 = blockIdx.z * k_per_z;
    C += (size_t)blockIdx.z * zstride;

    // Staging thread map: row = tid>>3 (+ p*16*WM per pass), seg = tid&7.
    // Source col-group is XOR-swizzled by row (row&7 is pass-invariant since
    // 16*WM % 8 == 0); LDS dest stays linear (wave-uniform base + lane*16,
    // required by global_load_lds). LDS[row][seg] = global[row][seg^(row&7)].
    const int srow = tid >> 3;
    const int scol = ((tid & 7) ^ (srow & 7)) * 8;
    const ushort* aP = A + (size_t)(m0 + srow) * lda + k0 + scol;
    const ushort* bP = B + (size_t)(n0 + srow) * ldb + k0 + scol;

    const int wr = (wave >> 1) * 32;         // row group (32 rows)
    const int wc = (wave & 1) * 64;          // col group (64 cols)
    const int fm = lane & 15;
    const int q  = lane >> 4;                // 0..3
    const int rx = fm & 7;                   // read-side swizzle key

    f32x4 acc[2][4] = {};

    auto stage = [&](int buf, int kk) {
        ushort* a_d = &As[buf][tid * 8];
        ushort* b_d = &Bs[buf][tid * 8];
        #pragma unroll
        for (int p = 0; p < 2; p++)
            gld_lds16(aP + kk + (size_t)(p * 16 * WM) * lda,
                      a_d + p * THREADS * 8);
        #pragma unroll
        for (int p = 0; p < PB; p++)
            gld_lds16(bP + kk + (size_t)(p * 16 * WM) * ldb,
                      b_d + p * THREADS * 8);
    };

    stage(0, 0);   // prefetch step 0

    for (int ks = 0; ks < ksteps; ++ks) {
        __syncthreads();   // buf[ks&1] staged (vmcnt drained); prev compute done
        if (ks + 1 < ksteps)
            stage((ks + 1) & 1, (ks + 1) * 64);

        const ushort* as = &As[ks & 1][0];
        const ushort* bs = &Bs[ks & 1][0];

        bf16x8 af[2][2], bf[2][4];
        #pragma unroll
        for (int kh = 0; kh < 2; kh++) {
            const int sg = ((kh * 4 + q) ^ rx) * 8;
            #pragma unroll
            for (int i = 0; i < 2; i++)
                af[kh][i] = *(const bf16x8*)&as[(wr + i * 16 + fm) * 64 + sg];
            #pragma unroll
            for (int i = 0; i < 4; i++)
                bf[kh][i] = *(const bf16x8*)&bs[(wc + i * 16 + fm) * 64 + sg];
        }
        #pragma unroll
        for (int kh = 0; kh < 2; kh++)
            #pragma unroll
            for (int mi = 0; mi < 2; mi++)
                #pragma unroll
                for (int ni = 0; ni < 4; ni++)
                    acc[mi][ni] = __builtin_amdgcn_mfma_f32_16x16x32_bf16(
                        af[kh][mi], bf[kh][ni], acc[mi][ni], 0, 0, 0);
    }

    // C/D layout: col = lane&15, row = (lane>>4)*4 + reg   [m89/m91 verified]
    const int rr = q * 4;
    #pragma unroll
    for (int ni = 0; ni < 4; ni++) {
        const int col = n0 + wc + ni * 16 + fm;
        const float bv = (EPI == 1) ? bias[col] : 0.0f;
        #pragma unroll
        for (int mi = 0; mi < 2; mi++) {
            const int row = m0 + wr + mi * 16 + rr;
            #pragma unroll
            for (int r = 0; r < 4; r++)
                C[(size_t)(row + r) * ldc + col] = acc[mi][ni][r] + bv;
        }
    }
}

// ---------------------------------------------------------------------------
// Reduce split-K partials of ax, apply SCALING*softmax weight, write bf16
// into Aext[:, 1024:1152]
// ---------------------------------------------------------------------------
__global__ __launch_bounds__(256) void ax_combine(
    const float* __restrict__ part, const float* __restrict__ wgt,
    ushort* __restrict__ Aext)
{
    int i = blockIdx.x * 256 + threadIdx.x;   // 0 .. 524287
    const int t = i >> 7, er = i & 127;
    const int SL = M_TOK * ERDIM;             // 524288
    float s = part[i] + part[i + SL] + part[i + 2 * SL] + part[i + 3 * SL];
    float w = wgt[t * 8 + (er >> 4)];
    Aext[(size_t)t * KEXT + KD + er] = f2bf(s * w);
}

// ---------------------------------------------------------------------------
extern "C" void kernel_launch(void* const* d_in, const int* in_sizes, int n_in,
                              void* d_out, int out_size, void* d_ws, size_t ws_size,
                              hipStream_t stream) {
    const float* x        = (const float*)d_in[0];
    const float* base_w   = (const float*)d_in[1];
    const float* base_b   = (const float*)d_in[2];
    const float* lora_A   = (const float*)d_in[3];
    const float* lora_B   = (const float*)d_in[4];
    const float* router_w = (const float*)d_in[5];
    const float* router_b = (const float*)d_in[6];
    float* out = (float*)d_out;

    // workspace layout (bytes): total ~20.6 MB
    char* ws = (char*)d_ws;
    ushort* Aext = (ushort*)(ws);               // 4096*1152*2 = 9,437,184
    ushort* Bext = (ushort*)(ws + 9437184);     // 1024*1152*2 = 2,359,296
    ushort* LAT  = (ushort*)(ws + 11796480);    //  128*1024*2 =   262,144
    float*  wgt  = (float*) (ws + 12058624);    //   4096*8*4  =   131,072
    float*  part = (float*) (ws + 12189696);    // 4*4096*128*4= 8,388,608

    // 1. fused: x->bf16 + router weights (blocks 0..4095) and bf16 packing
    //    of base_w / lora_B^T / lora_A^T (blocks 4096..9215)
    prep_router<<<9216, 256, 0, stream>>>(
        x, router_w, router_b, base_w, lora_A, lora_B, Aext, Bext, LAT, wgt);
    // 2. ax = x @ lora_A  (M=4096,N=128,K=1024) split-K=4, 64-row tiles,
    //    grid 256 -> one block per CU
    gemm_bt<2, 0><<<dim3(64, 1, 4), 256, 0, stream>>>(
        Aext, KEXT, LAT, KD, part, ERDIM, nullptr,
        /*k_per_z=*/256, /*zstride=*/M_TOK * ERDIM, /*ksteps=*/4);
    // 3. sax = bf16(SCALING * w * ax) into Aext[:,1024:1152]
    ax_combine<<<2048, 256, 0, stream>>>(part, wgt, Aext);
    // 4. out = [x|sax] @ [base_w|lora_B^T]^T + bias  (M=4096,N=1024,K=1152)
    //    512-thread blocks: 8 waves -> 2 waves/SIMD at grid 256
    gemm_bt<4, 1><<<dim3(32, 8, 1), 512, 0, stream>>>(
        Aext, KEXT, Bext, KEXT, out, NOUT, base_b,
        /*k_per_z=*/0, /*zstride=*/0, /*ksteps=*/18);
}

// Round 5
// 115.286 us; speedup vs baseline: 1.2389x; 1.0886x over previous
//
#include <hip/hip_runtime.h>
#include <cmath>

// Problem constants (B=4,S=1024,D=1024,O=1024,E=8,R=16,TOP_K=2)
#define M_TOK 4096
#define KD    1024
#define KEXT  1152     // 1024 + E*R
#define NOUT  1024
#define ERDIM 128      // E*R
#define SCALING 2.0f   // 32/16

typedef short bf16x8 __attribute__((ext_vector_type(8)));
typedef float f32x4  __attribute__((ext_vector_type(4)));

__device__ __forceinline__ ushort f2bf(float f) {
    union { float f; unsigned u; } v; v.f = f;
    unsigned r = v.u + 0x7fffu + ((v.u >> 16) & 1u);
    return (ushort)(r >> 16);
}

// async 16B global->LDS. C-style casts required for addrspace conversion.
typedef const unsigned int __attribute__((address_space(1)))* gas_ptr;
typedef unsigned int __attribute__((address_space(3)))* las_ptr;
__device__ __forceinline__ void gld_lds16(const ushort* g, ushort* l) {
    __builtin_amdgcn_global_load_lds((gas_ptr)g, (las_ptr)l, 16, 0, 0);
}

// ---------------------------------------------------------------------------
// Fused: blocks [0,4096): per-token x->bf16 + fp32/fp64 router + top-2
//        softmax weights.  blocks [4096,9216): pack base_w / lora_B^T /
//        lora_A^T to bf16.
// Router reduction: transposed fold (8 vals -> lane l holds expert l&7)
// in 7 fp64 exchanges + 3 plain butterflies = 10 fp64 shuffles/thread,
// vs 48 for the naive per-expert butterfly (DS-pipe was the bottleneck).
// ---------------------------------------------------------------------------
__global__ __launch_bounds__(256) void prep_router(
    const float* __restrict__ x, const float* __restrict__ rw,
    const float* __restrict__ rb, const float* __restrict__ base_w,
    const float* __restrict__ lora_A, const float* __restrict__ lora_B,
    ushort* __restrict__ Aext, ushort* __restrict__ Bext,
    ushort* __restrict__ LAT, float* __restrict__ wgt)
{
    const int tid = threadIdx.x;
    if (blockIdx.x >= 4096) {               // ---- pack path ----
        int i = (blockIdx.x - 4096) * 256 + tid;
        const int NB = NOUT * KEXT;         // 1,179,648
        if (i < NB) {
            int o = i / KEXT;
            int c = i - o * KEXT;
            float v = (c < KD) ? base_w[(size_t)o * KD + c]
                               : lora_B[(size_t)(c - KD) * NOUT + o];
            Bext[i] = f2bf(v);
        } else {
            int j = i - NB;                 // 0 .. 131071
            int er = j >> 10, d = j & 1023;
            int e = er >> 4, r = er & 15;
            LAT[j] = f2bf(lora_A[((size_t)e * KD + d) * 16 + r]);
        }
        return;
    }
    // ---- router/convert path ----
    const int t = blockIdx.x;
    const float4 xv = ((const float4*)(x + (size_t)t * KD))[tid];

    ushort4 xb;
    xb.x = f2bf(xv.x); xb.y = f2bf(xv.y); xb.z = f2bf(xv.z); xb.w = f2bf(xv.w);
    ((ushort4*)(Aext + (size_t)t * KEXT))[tid] = xb;

    double p[8];
    #pragma unroll
    for (int e = 0; e < 8; e++) {
        const float4 wv = ((const float4*)(rw + (size_t)e * KD))[tid];
        p[e] = (double)(xv.x * wv.x) + (double)(xv.y * wv.y) +
               (double)(xv.z * wv.z) + (double)(xv.w * wv.w);
    }

    const int wave = tid >> 6, lane = tid & 63;
    // --- transposed reduction: after fold, lane l holds expert l&7 ---
    double q0, q1, q2, q3, r0, r1, s;
    {   // level 0: exchange with lane^1; keep experts with bit0==lane bit0
        const bool b = lane & 1;
        double s0 = b ? p[0] : p[1];
        double s1 = b ? p[2] : p[3];
        double s2 = b ? p[4] : p[5];
        double s3 = b ? p[6] : p[7];
        q0 = (b ? p[1] : p[0]) + __shfl_xor(s0, 1);
        q1 = (b ? p[3] : p[2]) + __shfl_xor(s1, 1);
        q2 = (b ? p[5] : p[4]) + __shfl_xor(s2, 1);
        q3 = (b ? p[7] : p[6]) + __shfl_xor(s3, 1);
    }
    {   // level 1: exchange with lane^2; keep experts with bit1==lane bit1
        const bool b = (lane >> 1) & 1;
        double s0 = b ? q0 : q1;
        double s1 = b ? q2 : q3;
        r0 = (b ? q1 : q0) + __shfl_xor(s0, 2);
        r1 = (b ? q3 : q2) + __shfl_xor(s1, 2);
    }
    {   // level 2: exchange with lane^4; keep expert with bit2==lane bit2
        const bool b = (lane >> 2) & 1;
        double s0 = b ? r0 : r1;
        s = (b ? r1 : r0) + __shfl_xor(s0, 4);
    }
    // now lane l holds expert (l&7) summed over its 8-lane group
    s += __shfl_xor(s, 8);
    s += __shfl_xor(s, 16);
    s += __shfl_xor(s, 32);
    // every lane holds the full 64-lane sum for expert lane&7

    __shared__ double red[4][8];
    __shared__ float  lg[8];
    if (lane < 8) red[wave][lane] = s;
    __syncthreads();
    if (tid < 8) {
        double sum = red[0][tid] + red[1][tid] + red[2][tid] + red[3][tid]
                   + (double)rb[tid];
        lg[tid] = (float)sum;
    }
    __syncthreads();
    if (tid < 8) {
        float my = lg[tid];
        float m1 = -INFINITY, m2 = -INFINITY;
        #pragma unroll
        for (int i = 0; i < 8; i++) {
            float v = lg[i];
            if (v > m1) { m2 = m1; m1 = v; }
            else if (v > m2) { m2 = v; }
        }
        float denom = 0.f;
        #pragma unroll
        for (int i = 0; i < 8; i++)
            if (lg[i] >= m2) denom += expf(lg[i] - m1);
        float w = (my >= m2) ? expf(my - m1) / denom : 0.f;
        wgt[t * 8 + tid] = SCALING * w;
    }
}

// ---------------------------------------------------------------------------
// bf16 MFMA GEMM, C = A @ B^T.  Tile (WM*32) x 128, BK=64, double-buffered
// LDS, XOR-swizzled staging (bank-uniform ds_read_b128 at 128B row stride).
// Block = WM*2 waves; each wave computes 32x64 via 2x4 frags of 16x16x32.
//   WM=4: 512 threads, 128x128 tile (main GEMM, 2 waves/SIMD at grid 256)
//   WM=2: 256 threads,  64x128 tile (ax GEMM, grid 256 over all CUs)
// EPI==0: store fp32 partial (split-K slab); EPI==1: store fp32 + bias.
// ---------------------------------------------------------------------------
template <int WM, int EPI>
__global__ __launch_bounds__(WM * 128) void gemm_bt(
    const ushort* __restrict__ A, int lda,
    const ushort* __restrict__ B, int ldb,
    float* __restrict__ C, int ldc,
    const float* __restrict__ bias,
    int k_per_z, int zstride, int ksteps)
{
    constexpr int THREADS = WM * 128;
    constexpr int TM = WM * 32;      // tile rows
    constexpr int PB = 8 / WM;       // B staging passes (A is always 2)

    __shared__ __attribute__((aligned(16))) ushort As[2][TM * 64];
    __shared__ __attribute__((aligned(16))) ushort Bs[2][128 * 64];

    const int tid  = threadIdx.x;
    const int wave = tid >> 6;
    const int lane = tid & 63;
    const int m0 = blockIdx.x * TM;
    const int n0 = blockIdx.y * 128;
    const int k0 = blockIdx.z * k_per_z;
    C += (size_t)blockIdx.z * zstride;

    // Staging thread map: row = tid>>3 (+ p*16*WM per pass), seg = tid&7.
    // Source col-group is XOR-swizzled by row (row&7 is pass-invariant since
    // 16*WM % 8 == 0); LDS dest stays linear (wave-uniform base + lane*16,
    // required by global_load_lds). LDS[row][seg] = global[row][seg^(row&7)].
    const int srow = tid >> 3;
    const int scol = ((tid & 7) ^ (srow & 7)) * 8;
    const ushort* aP = A + (size_t)(m0 + srow) * lda + k0 + scol;
    const ushort* bP = B + (size_t)(n0 + srow) * ldb + k0 + scol;

    const int wr = (wave >> 1) * 32;         // row group (32 rows)
    const int wc = (wave & 1) * 64;          // col group (64 cols)
    const int fm = lane & 15;
    const int q  = lane >> 4;                // 0..3
    const int rx = fm & 7;                   // read-side swizzle key

    f32x4 acc[2][4] = {};

    auto stage = [&](int buf, int kk) {
        ushort* a_d = &As[buf][tid * 8];
        ushort* b_d = &Bs[buf][tid * 8];
        #pragma unroll
        for (int p = 0; p < 2; p++)
            gld_lds16(aP + kk + (size_t)(p * 16 * WM) * lda,
                      a_d + p * THREADS * 8);
        #pragma unroll
        for (int p = 0; p < PB; p++)
            gld_lds16(bP + kk + (size_t)(p * 16 * WM) * ldb,
                      b_d + p * THREADS * 8);
    };

    stage(0, 0);   // prefetch step 0

    for (int ks = 0; ks < ksteps; ++ks) {
        __syncthreads();   // buf[ks&1] staged (vmcnt drained); prev compute done
        if (ks + 1 < ksteps)
            stage((ks + 1) & 1, (ks + 1) * 64);

        const ushort* as = &As[ks & 1][0];
        const ushort* bs = &Bs[ks & 1][0];

        bf16x8 af[2][2], bf[2][4];
        #pragma unroll
        for (int kh = 0; kh < 2; kh++) {
            const int sg = ((kh * 4 + q) ^ rx) * 8;
            #pragma unroll
            for (int i = 0; i < 2; i++)
                af[kh][i] = *(const bf16x8*)&as[(wr + i * 16 + fm) * 64 + sg];
            #pragma unroll
            for (int i = 0; i < 4; i++)
                bf[kh][i] = *(const bf16x8*)&bs[(wc + i * 16 + fm) * 64 + sg];
        }
        #pragma unroll
        for (int kh = 0; kh < 2; kh++)
            #pragma unroll
            for (int mi = 0; mi < 2; mi++)
                #pragma unroll
                for (int ni = 0; ni < 4; ni++)
                    acc[mi][ni] = __builtin_amdgcn_mfma_f32_16x16x32_bf16(
                        af[kh][mi], bf[kh][ni], acc[mi][ni], 0, 0, 0);
    }

    // C/D layout: col = lane&15, row = (lane>>4)*4 + reg   [m89/m91 verified]
    const int rr = q * 4;
    #pragma unroll
    for (int ni = 0; ni < 4; ni++) {
        const int col = n0 + wc + ni * 16 + fm;
        const float bv = (EPI == 1) ? bias[col] : 0.0f;
        #pragma unroll
        for (int mi = 0; mi < 2; mi++) {
            const int row = m0 + wr + mi * 16 + rr;
            #pragma unroll
            for (int r = 0; r < 4; r++)
                C[(size_t)(row + r) * ldc + col] = acc[mi][ni][r] + bv;
        }
    }
}

// ---------------------------------------------------------------------------
// Reduce split-K partials of ax, apply SCALING*softmax weight, write bf16
// into Aext[:, 1024:1152]
// ---------------------------------------------------------------------------
__global__ __launch_bounds__(256) void ax_combine(
    const float* __restrict__ part, const float* __restrict__ wgt,
    ushort* __restrict__ Aext)
{
    int i = blockIdx.x * 256 + threadIdx.x;   // 0 .. 524287
    const int t = i >> 7, er = i & 127;
    const int SL = M_TOK * ERDIM;             // 524288
    float s = part[i] + part[i + SL] + part[i + 2 * SL] + part[i + 3 * SL];
    float w = wgt[t * 8 + (er >> 4)];
    Aext[(size_t)t * KEXT + KD + er] = f2bf(s * w);
}

// ---------------------------------------------------------------------------
extern "C" void kernel_launch(void* const* d_in, const int* in_sizes, int n_in,
                              void* d_out, int out_size, void* d_ws, size_t ws_size,
                              hipStream_t stream) {
    const float* x        = (const float*)d_in[0];
    const float* base_w   = (const float*)d_in[1];
    const float* base_b   = (const float*)d_in[2];
    const float* lora_A   = (const float*)d_in[3];
    const float* lora_B   = (const float*)d_in[4];
    const float* router_w = (const float*)d_in[5];
    const float* router_b = (const float*)d_in[6];
    float* out = (float*)d_out;

    // workspace layout (bytes): total ~20.6 MB
    char* ws = (char*)d_ws;
    ushort* Aext = (ushort*)(ws);               // 4096*1152*2 = 9,437,184
    ushort* Bext = (ushort*)(ws + 9437184);     // 1024*1152*2 = 2,359,296
    ushort* LAT  = (ushort*)(ws + 11796480);    //  128*1024*2 =   262,144
    float*  wgt  = (float*) (ws + 12058624);    //   4096*8*4  =   131,072
    float*  part = (float*) (ws + 12189696);    // 4*4096*128*4= 8,388,608

    // 1. fused: x->bf16 + router weights (blocks 0..4095) and bf16 packing
    //    of base_w / lora_B^T / lora_A^T (blocks 4096..9215)
    prep_router<<<9216, 256, 0, stream>>>(
        x, router_w, router_b, base_w, lora_A, lora_B, Aext, Bext, LAT, wgt);
    // 2. ax = x @ lora_A  (M=4096,N=128,K=1024) split-K=4, 64-row tiles,
    //    grid 256 -> one block per CU
    gemm_bt<2, 0><<<dim3(64, 1, 4), 256, 0, stream>>>(
        Aext, KEXT, LAT, KD, part, ERDIM, nullptr,
        /*k_per_z=*/256, /*zstride=*/M_TOK * ERDIM, /*ksteps=*/4);
    // 3. sax = bf16(SCALING * w * ax) into Aext[:,1024:1152]
    ax_combine<<<2048, 256, 0, stream>>>(part, wgt, Aext);
    // 4. out = [x|sax] @ [base_w|lora_B^T]^T + bias  (M=4096,N=1024,K=1152)
    //    512-thread blocks: 8 waves -> 2 waves/SIMD at grid 256
    gemm_bt<4, 1><<<dim3(32, 8, 1), 512, 0, stream>>>(
        Aext, KEXT, Bext, KEXT, out, NOUT, base_b,
        /*k_per_z=*/0, /*zstride=*/0, /*ksteps=*/18);
}

// Round 6
// 112.325 us; speedup vs baseline: 1.2715x; 1.0264x over previous
//
#include <hip/hip_runtime.h>
#include <cmath>

// Problem constants (B=4,S=1024,D=1024,O=1024,E=8,R=16,TOP_K=2)
#define M_TOK 4096
#define KD    1024
#define KEXT  1152     // 1024 + E*R
#define NOUT  1024
#define ERDIM 128      // E*R
#define SCALING 2.0f   // 32/16

typedef short bf16x8 __attribute__((ext_vector_type(8)));
typedef float f32x4  __attribute__((ext_vector_type(4)));

__device__ __forceinline__ ushort f2bf(float f) {
    union { float f; unsigned u; } v; v.f = f;
    unsigned r = v.u + 0x7fffu + ((v.u >> 16) & 1u);
    return (ushort)(r >> 16);
}

// async 16B global->LDS. C-style casts required for addrspace conversion.
typedef const unsigned int __attribute__((address_space(1)))* gas_ptr;
typedef unsigned int __attribute__((address_space(3)))* las_ptr;
__device__ __forceinline__ void gld_lds16(const ushort* g, ushort* l) {
    __builtin_amdgcn_global_load_lds((gas_ptr)g, (las_ptr)l, 16, 0, 0);
}

// ---------------------------------------------------------------------------
// Fused: blocks [0,4096): per-token x->bf16 + fp32/fp64 router + top-2
//        softmax weights.  blocks [4096,9216): pack base_w / lora_B^T /
//        lora_A^T to bf16.
// Router reduction: transposed fold (7 fp64 exchanges) + 3 butterflies =
// 10 fp64 shuffles/thread (vs 48 naive; DS-pipe was the bottleneck — R5).
// ---------------------------------------------------------------------------
__global__ __launch_bounds__(256) void prep_router(
    const float* __restrict__ x, const float* __restrict__ rw,
    const float* __restrict__ rb, const float* __restrict__ base_w,
    const float* __restrict__ lora_A, const float* __restrict__ lora_B,
    ushort* __restrict__ Aext, ushort* __restrict__ Bext,
    ushort* __restrict__ LAT, float* __restrict__ wgt)
{
    const int tid = threadIdx.x;
    if (blockIdx.x >= 4096) {               // ---- pack path ----
        int i = (blockIdx.x - 4096) * 256 + tid;
        const int NB = NOUT * KEXT;         // 1,179,648
        if (i < NB) {
            int o = i / KEXT;
            int c = i - o * KEXT;
            float v = (c < KD) ? base_w[(size_t)o * KD + c]
                               : lora_B[(size_t)(c - KD) * NOUT + o];
            Bext[i] = f2bf(v);
        } else {
            int j = i - NB;                 // 0 .. 131071
            int er = j >> 10, d = j & 1023;
            int e = er >> 4, r = er & 15;
            LAT[j] = f2bf(lora_A[((size_t)e * KD + d) * 16 + r]);
        }
        return;
    }
    // ---- router/convert path ----
    const int t = blockIdx.x;
    const float4 xv = ((const float4*)(x + (size_t)t * KD))[tid];

    ushort4 xb;
    xb.x = f2bf(xv.x); xb.y = f2bf(xv.y); xb.z = f2bf(xv.z); xb.w = f2bf(xv.w);
    ((ushort4*)(Aext + (size_t)t * KEXT))[tid] = xb;

    double p[8];
    #pragma unroll
    for (int e = 0; e < 8; e++) {
        const float4 wv = ((const float4*)(rw + (size_t)e * KD))[tid];
        p[e] = (double)(xv.x * wv.x) + (double)(xv.y * wv.y) +
               (double)(xv.z * wv.z) + (double)(xv.w * wv.w);
    }

    const int wave = tid >> 6, lane = tid & 63;
    // --- transposed reduction: after fold, lane l holds expert l&7 ---
    double q0, q1, q2, q3, r0, r1, s;
    {   const bool b = lane & 1;
        double s0 = b ? p[0] : p[1];
        double s1 = b ? p[2] : p[3];
        double s2 = b ? p[4] : p[5];
        double s3 = b ? p[6] : p[7];
        q0 = (b ? p[1] : p[0]) + __shfl_xor(s0, 1);
        q1 = (b ? p[3] : p[2]) + __shfl_xor(s1, 1);
        q2 = (b ? p[5] : p[4]) + __shfl_xor(s2, 1);
        q3 = (b ? p[7] : p[6]) + __shfl_xor(s3, 1);
    }
    {   const bool b = (lane >> 1) & 1;
        double s0 = b ? q0 : q1;
        double s1 = b ? q2 : q3;
        r0 = (b ? q1 : q0) + __shfl_xor(s0, 2);
        r1 = (b ? q3 : q2) + __shfl_xor(s1, 2);
    }
    {   const bool b = (lane >> 2) & 1;
        double s0 = b ? r0 : r1;
        s = (b ? r1 : r0) + __shfl_xor(s0, 4);
    }
    s += __shfl_xor(s, 8);
    s += __shfl_xor(s, 16);
    s += __shfl_xor(s, 32);

    __shared__ double red[4][8];
    __shared__ float  lg[8];
    if (lane < 8) red[wave][lane] = s;
    __syncthreads();
    if (tid < 8) {
        double sum = red[0][tid] + red[1][tid] + red[2][tid] + red[3][tid]
                   + (double)rb[tid];
        lg[tid] = (float)sum;
    }
    __syncthreads();
    if (tid < 8) {
        float my = lg[tid];
        float m1 = -INFINITY, m2 = -INFINITY;
        #pragma unroll
        for (int i = 0; i < 8; i++) {
            float v = lg[i];
            if (v > m1) { m2 = m1; m1 = v; }
            else if (v > m2) { m2 = v; }
        }
        float denom = 0.f;
        #pragma unroll
        for (int i = 0; i < 8; i++)
            if (lg[i] >= m2) denom += expf(lg[i] - m1);
        float w = (my >= m2) ? expf(my - m1) / denom : 0.f;
        wgt[t * 8 + tid] = SCALING * w;
    }
}

// ---------------------------------------------------------------------------
// Main GEMM: out = Aext @ Bext^T + bias.  Tile 128x64, grid (32,16) = 512
// blocks -> 2 independent blocks/CU (barrier staggering, m114). 256 thr =
// 4 waves, each 32x64 via 2x4 frags of 16x16x32. BK=64, dbuf, XOR swizzle.
// LDS 48 KB/block -> two co-resident. acc[2][4] keeps VGPR low for
// 2-wave/SIMD co-residency.
// ---------------------------------------------------------------------------
__global__ __launch_bounds__(256) void gemm_main(
    const ushort* __restrict__ A, const ushort* __restrict__ B,
    float* __restrict__ C, const float* __restrict__ bias, int ksteps)
{
    __shared__ __attribute__((aligned(16))) ushort As[2][128 * 64];
    __shared__ __attribute__((aligned(16))) ushort Bs[2][64 * 64];

    const int tid  = threadIdx.x;
    const int wave = tid >> 6;
    const int lane = tid & 63;
    const int m0 = blockIdx.x * 128;
    const int n0 = blockIdx.y * 64;

    // Staging map: row = tid>>3 (+p*32), seg = tid&7, source col-group
    // XOR-swizzled by row (row&7 pass-invariant). LDS[row][s]=G[row][s^(row&7)].
    const int srow = tid >> 3;               // 0..31
    const int scol = ((tid & 7) ^ (srow & 7)) * 8;
    const ushort* aP = A + (size_t)(m0 + srow) * KEXT + scol;
    const ushort* bP = B + (size_t)(n0 + srow) * KEXT + scol;

    const int wr = wave * 32;                // 4 row-stripes of 32
    const int fm = lane & 15;
    const int q  = lane >> 4;                // 0..3
    const int rx = fm & 7;                   // read-side swizzle key

    f32x4 acc[2][4] = {};

    auto stage = [&](int buf, int kk) {
        ushort* a_d = &As[buf][tid * 8];
        ushort* b_d = &Bs[buf][tid * 8];
        #pragma unroll
        for (int p = 0; p < 4; p++)
            gld_lds16(aP + kk + (size_t)(p * 32) * KEXT, a_d + p * 2048);
        #pragma unroll
        for (int p = 0; p < 2; p++)
            gld_lds16(bP + kk + (size_t)(p * 32) * KEXT, b_d + p * 2048);
    };

    stage(0, 0);   // prefetch step 0

    for (int ks = 0; ks < ksteps; ++ks) {
        __syncthreads();   // buf[ks&1] staged (vmcnt drained); prev compute done
        if (ks + 1 < ksteps)
            stage((ks + 1) & 1, (ks + 1) * 64);

        const ushort* as = &As[ks & 1][0];
        const ushort* bs = &Bs[ks & 1][0];

        bf16x8 af[2][2], bf[2][4];
        #pragma unroll
        for (int kh = 0; kh < 2; kh++) {
            const int sg = ((kh * 4 + q) ^ rx) * 8;
            #pragma unroll
            for (int i = 0; i < 2; i++)
                af[kh][i] = *(const bf16x8*)&as[(wr + i * 16 + fm) * 64 + sg];
            #pragma unroll
            for (int j = 0; j < 4; j++)
                bf[kh][j] = *(const bf16x8*)&bs[(j * 16 + fm) * 64 + sg];
        }
        #pragma unroll
        for (int kh = 0; kh < 2; kh++)
            #pragma unroll
            for (int mi = 0; mi < 2; mi++)
                #pragma unroll
                for (int ni = 0; ni < 4; ni++)
                    acc[mi][ni] = __builtin_amdgcn_mfma_f32_16x16x32_bf16(
                        af[kh][mi], bf[kh][ni], acc[mi][ni], 0, 0, 0);
    }

    // C/D layout: col = lane&15, row = (lane>>4)*4 + reg   [m89/m91 verified]
    const int rr = q * 4;
    #pragma unroll
    for (int ni = 0; ni < 4; ni++) {
        const int col = n0 + ni * 16 + fm;
        const float bv = bias[col];
        #pragma unroll
        for (int mi = 0; mi < 2; mi++) {
            const int row = m0 + wr + mi * 16 + rr;
            #pragma unroll
            for (int r = 0; r < 4; r++)
                C[(size_t)(row + r) * NOUT + col] = acc[mi][ni][r] + bv;
        }
    }
}

// ---------------------------------------------------------------------------
// ax GEMM (split-K): C = A @ B^T partials. Tile 64x128, BK=64, dbuf,
// swizzle; 4 waves of 32x64. Grid (64,1,4) -> one block per CU.
// ---------------------------------------------------------------------------
__global__ __launch_bounds__(256) void gemm_ax(
    const ushort* __restrict__ A, int lda,
    const ushort* __restrict__ B, int ldb,
    float* __restrict__ C, int ldc,
    int k_per_z, int zstride, int ksteps)
{
    __shared__ __attribute__((aligned(16))) ushort As[2][64 * 64];
    __shared__ __attribute__((aligned(16))) ushort Bs[2][128 * 64];

    const int tid  = threadIdx.x;
    const int wave = tid >> 6;
    const int lane = tid & 63;
    const int m0 = blockIdx.x * 64;
    const int k0 = blockIdx.z * k_per_z;
    C += (size_t)blockIdx.z * zstride;

    const int srow = tid >> 3;
    const int scol = ((tid & 7) ^ (srow & 7)) * 8;
    const ushort* aP = A + (size_t)(m0 + srow) * lda + k0 + scol;
    const ushort* bP = B + (size_t)(srow) * ldb + k0 + scol;

    const int wr = (wave >> 1) * 32;         // row group (32 rows)
    const int wc = (wave & 1) * 64;          // col group (64 cols)
    const int fm = lane & 15;
    const int q  = lane >> 4;
    const int rx = fm & 7;

    f32x4 acc[2][4] = {};

    auto stage = [&](int buf, int kk) {
        ushort* a_d = &As[buf][tid * 8];
        ushort* b_d = &Bs[buf][tid * 8];
        #pragma unroll
        for (int p = 0; p < 2; p++)
            gld_lds16(aP + kk + (size_t)(p * 32) * lda, a_d + p * 2048);
        #pragma unroll
        for (int p = 0; p < 4; p++)
            gld_lds16(bP + kk + (size_t)(p * 32) * ldb, b_d + p * 2048);
    };

    stage(0, 0);

    for (int ks = 0; ks < ksteps; ++ks) {
        __syncthreads();
        if (ks + 1 < ksteps)
            stage((ks + 1) & 1, (ks + 1) * 64);

        const ushort* as = &As[ks & 1][0];
        const ushort* bs = &Bs[ks & 1][0];

        bf16x8 af[2][2], bf[2][4];
        #pragma unroll
        for (int kh = 0; kh < 2; kh++) {
            const int sg = ((kh * 4 + q) ^ rx) * 8;
            #pragma unroll
            for (int i = 0; i < 2; i++)
                af[kh][i] = *(const bf16x8*)&as[(wr + i * 16 + fm) * 64 + sg];
            #pragma unroll
            for (int j = 0; j < 4; j++)
                bf[kh][j] = *(const bf16x8*)&bs[(wc + j * 16 + fm) * 64 + sg];
        }
        #pragma unroll
        for (int kh = 0; kh < 2; kh++)
            #pragma unroll
            for (int mi = 0; mi < 2; mi++)
                #pragma unroll
                for (int ni = 0; ni < 4; ni++)
                    acc[mi][ni] = __builtin_amdgcn_mfma_f32_16x16x32_bf16(
                        af[kh][mi], bf[kh][ni], acc[mi][ni], 0, 0, 0);
    }

    const int rr = q * 4;
    #pragma unroll
    for (int ni = 0; ni < 4; ni++) {
        const int col = wc + ni * 16 + fm;
        #pragma unroll
        for (int mi = 0; mi < 2; mi++) {
            const int row = m0 + wr + mi * 16 + rr;
            #pragma unroll
            for (int r = 0; r < 4; r++)
                C[(size_t)(row + r) * ldc + col] = acc[mi][ni][r];
        }
    }
}

// ---------------------------------------------------------------------------
// Reduce split-K partials of ax, apply SCALING*softmax weight, write bf16
// into Aext[:, 1024:1152]
// ---------------------------------------------------------------------------
__global__ __launch_bounds__(256) void ax_combine(
    const float* __restrict__ part, const float* __restrict__ wgt,
    ushort* __restrict__ Aext)
{
    int i = blockIdx.x * 256 + threadIdx.x;   // 0 .. 524287
    const int t = i >> 7, er = i & 127;
    const int SL = M_TOK * ERDIM;             // 524288
    float s = part[i] + part[i + SL] + part[i + 2 * SL] + part[i + 3 * SL];
    float w = wgt[t * 8 + (er >> 4)];
    Aext[(size_t)t * KEXT + KD + er] = f2bf(s * w);
}

// ---------------------------------------------------------------------------
extern "C" void kernel_launch(void* const* d_in, const int* in_sizes, int n_in,
                              void* d_out, int out_size, void* d_ws, size_t ws_size,
                              hipStream_t stream) {
    const float* x        = (const float*)d_in[0];
    const float* base_w   = (const float*)d_in[1];
    const float* base_b   = (const float*)d_in[2];
    const float* lora_A   = (const float*)d_in[3];
    const float* lora_B   = (const float*)d_in[4];
    const float* router_w = (const float*)d_in[5];
    const float* router_b = (const float*)d_in[6];
    float* out = (float*)d_out;

    // workspace layout (bytes): total ~20.6 MB
    char* ws = (char*)d_ws;
    ushort* Aext = (ushort*)(ws);               // 4096*1152*2 = 9,437,184
    ushort* Bext = (ushort*)(ws + 9437184);     // 1024*1152*2 = 2,359,296
    ushort* LAT  = (ushort*)(ws + 11796480);    //  128*1024*2 =   262,144
    float*  wgt  = (float*) (ws + 12058624);    //   4096*8*4  =   131,072
    float*  part = (float*) (ws + 12189696);    // 4*4096*128*4= 8,388,608

    // 1. fused: x->bf16 + router weights (blocks 0..4095) and bf16 packing
    //    of base_w / lora_B^T / lora_A^T (blocks 4096..9215)
    prep_router<<<9216, 256, 0, stream>>>(
        x, router_w, router_b, base_w, lora_A, lora_B, Aext, Bext, LAT, wgt);
    // 2. ax = x @ lora_A  (M=4096,N=128,K=1024) split-K=4, 64-row tiles,
    //    grid 256 -> one block per CU
    gemm_ax<<<dim3(64, 1, 4), 256, 0, stream>>>(
        Aext, KEXT, LAT, KD, part, ERDIM,
        /*k_per_z=*/256, /*zstride=*/M_TOK * ERDIM, /*ksteps=*/4);
    // 3. sax = bf16(SCALING * w * ax) into Aext[:,1024:1152]
    ax_combine<<<2048, 256, 0, stream>>>(part, wgt, Aext);
    // 4. out = [x|sax] @ [base_w|lora_B^T]^T + bias  (M=4096,N=1024,K=1152)
    //    128x64 tiles, grid (32,16)=512 -> 2 independent blocks/CU
    gemm_main<<<dim3(32, 16), 256, 0, stream>>>(
        Aext, Bext, out, base_b, /*ksteps=*/18);
}